// Round 4
// baseline (155.778 us; speedup 1.0000x reference)
//
#include <hip/hip_runtime.h>
#include <hip/hip_bf16.h>

// Row-wise cosine hinge loss, wave-per-row persistent version with DPP
// (VALU-pipe) wave reduction instead of ds_swizzle shuffles.
//   j = (i + 1 + neg_idx[i]) % B
//   hinge_i = relu(1 - cos(t_i, o_i) + cos(t_j, o_i))
//   out = sum_i hinge_i / B

#define EPS 1e-6f

// Native vector type (HIP_vector_type is a struct; the nontemporal builtin
// and cleanest codegen want the clang ext_vector type).
typedef float f4 __attribute__((ext_vector_type(4)));

// One reduction step on the VALU pipe via DPP.
// After the 6 steps below, lane 63 holds the 64-lane sum (rocPRIM sequence).
#define DPP_STEP(x, ctrl, rm, bm)                                             \
    x += __int_as_float(__builtin_amdgcn_update_dpp(                          \
        0, __float_as_int(x), (ctrl), (rm), (bm), true))

__device__ __forceinline__ float dpp_wave_sum(float x) {
    DPP_STEP(x, 0x111, 0xf, 0xf);  // row_shr:1
    DPP_STEP(x, 0x112, 0xf, 0xf);  // row_shr:2
    DPP_STEP(x, 0x114, 0xf, 0xe);  // row_shr:4
    DPP_STEP(x, 0x118, 0xf, 0xc);  // row_shr:8
    DPP_STEP(x, 0x142, 0xa, 0xf);  // row_bcast:15
    DPP_STEP(x, 0x143, 0xc, 0xf);  // row_bcast:31
    return x;                      // valid in lane 63
}

__global__ __launch_bounds__(256) void hinge_cos_kernel(
    const float* __restrict__ outm,   // [B, D]
    const float* __restrict__ tgt,    // [B, D]
    const int*   __restrict__ negidx, // [B]
    float* __restrict__ res,          // [1] scalar (pre-zeroed)
    int B, int D, float invB) {

    const int lane  = threadIdx.x & 63;
    const int wave  = threadIdx.x >> 6;
    const int wpb   = blockDim.x >> 6;           // waves per block (4)
    const int gwave = blockIdx.x * wpb + wave;   // global wave id
    const int nwav  = gridDim.x * wpb;           // total waves
    const int CH    = 4;                         // f4 chunks per lane (1024/4/64)

    float acc = 0.f;                             // per-wave hinge sum (lane 63)

    for (int i = gwave; i < B; i += nwav) {
        int j = i + 1 + negidx[i];
        if (j >= B) j -= B;

        const f4* o4 = (const f4*)(outm + (size_t)i * D);
        const f4* t4 = (const f4*)(tgt  + (size_t)i * D);
        const f4* n4 = (const f4*)(tgt  + (size_t)j * D);

        // Issue all 12 independent 16B loads before any use.
        f4 o[CH], t[CH], n[CH];
#pragma unroll
        for (int k = 0; k < CH; ++k)
            o[k] = __builtin_nontemporal_load(&o4[lane + 64 * k]);  // single-use stream
#pragma unroll
        for (int k = 0; k < CH; ++k) t[k] = t4[lane + 64 * k];
#pragma unroll
        for (int k = 0; k < CH; ++k) n[k] = n4[lane + 64 * k];

        float d_to = 0.f, d_no = 0.f, oo = 0.f, tt = 0.f, nn = 0.f;
#pragma unroll
        for (int k = 0; k < CH; ++k) {
            d_to += o[k].x * t[k].x + o[k].y * t[k].y + o[k].z * t[k].z + o[k].w * t[k].w;
            d_no += o[k].x * n[k].x + o[k].y * n[k].y + o[k].z * n[k].z + o[k].w * n[k].w;
            oo   += o[k].x * o[k].x + o[k].y * o[k].y + o[k].z * o[k].z + o[k].w * o[k].w;
            tt   += t[k].x * t[k].x + t[k].y * t[k].y + t[k].z * t[k].z + t[k].w * t[k].w;
            nn   += n[k].x * n[k].x + n[k].y * n[k].y + n[k].z * n[k].z + n[k].w * n[k].w;
        }

        // VALU-pipe reductions; results land in lane 63.
        d_to = dpp_wave_sum(d_to);
        d_no = dpp_wave_sum(d_no);
        oo   = dpp_wave_sum(oo);
        tt   = dpp_wave_sum(tt);
        nn   = dpp_wave_sum(nn);

        if (lane == 63) {
            float no   = sqrtf(oo);
            float den1 = fmaxf(sqrtf(tt) * no, EPS);
            float den2 = fmaxf(sqrtf(nn) * no, EPS);
            float hinge = 1.f - d_to / den1 + d_no / den2;
            if (hinge > 0.f) acc += hinge;
        }
    }

    // Block-level: lane 63 of each wave holds its partial; one atomic per block.
    __shared__ float red[4];
    if (lane == 63) red[wave] = acc;
    __syncthreads();
    if (threadIdx.x == 0) {
        float s = 0.f;
#pragma unroll
        for (int w = 0; w < 4; ++w) s += red[w];
        atomicAdd(res, s * invB);
    }
}

extern "C" void kernel_launch(void* const* d_in, const int* in_sizes, int n_in,
                              void* d_out, int out_size, void* d_ws, size_t ws_size,
                              hipStream_t stream) {
    const float* outm   = (const float*)d_in[0];
    const float* tgt    = (const float*)d_in[1];
    const int*   negidx = (const int*)d_in[2];
    float* res = (float*)d_out;

    const int B = in_sizes[2];
    const int D = in_sizes[0] / B;

    (void)hipMemsetAsync(res, 0, sizeof(float), stream);

    // 2048 blocks x 256 thr = 8192 waves; each wave handles 2 rows.
    hinge_cos_kernel<<<2048, 256, 0, stream>>>(outm, tgt, negidx, res, B, D,
                                               1.0f / (float)B);
}

// Round 5
// 147.509 us; speedup vs baseline: 1.0561x; 1.0561x over previous
//
#include <hip/hip_runtime.h>
#include <hip/hip_bf16.h>

// Row-wise cosine hinge loss.
//   j = (i + 1 + neg_idx[i]) % B
//   hinge_i = relu(1 - cos(t_i, o_i) + cos(t_j, o_i))
//   out = sum_i hinge_i / B
//
// Wave-per-row, TWO rows per iteration: 24 independent 16B loads issued
// before any consumption (~96 data VGPRs). __launch_bounds__(256,4) caps
// occupancy at 4 waves/EU so the allocator may use up to 128 VGPRs and the
// scheduler keeps the loads hoisted instead of serializing them in batches
// of 3 (the R4 failure mode: VGPR_Count=32, vmcnt(0) convoy per batch).

#define EPS 1e-6f

typedef float f4 __attribute__((ext_vector_type(4)));

// VALU-pipe wave reduction via DPP; lane 63 holds the 64-lane sum.
#define DPP_STEP(x, ctrl, rm, bm)                                             \
    x += __int_as_float(__builtin_amdgcn_update_dpp(                          \
        0, __float_as_int(x), (ctrl), (rm), (bm), true))

__device__ __forceinline__ float dpp_wave_sum(float x) {
    DPP_STEP(x, 0x111, 0xf, 0xf);  // row_shr:1
    DPP_STEP(x, 0x112, 0xf, 0xf);  // row_shr:2
    DPP_STEP(x, 0x114, 0xf, 0xe);  // row_shr:4
    DPP_STEP(x, 0x118, 0xf, 0xc);  // row_shr:8
    DPP_STEP(x, 0x142, 0xa, 0xf);  // row_bcast:15
    DPP_STEP(x, 0x143, 0xc, 0xf);  // row_bcast:31
    return x;                      // valid in lane 63
}

__global__ __launch_bounds__(256, 4) void hinge_cos_kernel(
    const float* __restrict__ outm,   // [B, D]
    const float* __restrict__ tgt,    // [B, D]
    const int*   __restrict__ negidx, // [B]
    float* __restrict__ res,          // [1] scalar (pre-zeroed)
    int B, int D, float invB) {

    const int lane  = threadIdx.x & 63;
    const int wave  = threadIdx.x >> 6;
    const int wpb   = blockDim.x >> 6;           // 4
    const int gwave = blockIdx.x * wpb + wave;
    const int nwav  = gridDim.x * wpb;           // 4096
    const int CH    = 4;                         // f4 chunks per lane per row

    float acc = 0.f;                             // per-wave hinge sum (lane 63)

    for (int i = 2 * gwave; i < B; i += 2 * nwav) {
        const int i0 = i, i1 = i + 1;            // B even -> i1 < B
        int j0 = i0 + 1 + negidx[i0]; if (j0 >= B) j0 -= B;
        int j1 = i1 + 1 + negidx[i1]; if (j1 >= B) j1 -= B;

        const f4* o0 = (const f4*)(outm + (size_t)i0 * D);
        const f4* o1 = (const f4*)(outm + (size_t)i1 * D);
        const f4* t0 = (const f4*)(tgt  + (size_t)i0 * D);
        const f4* t1 = (const f4*)(tgt  + (size_t)i1 * D);
        const f4* n0 = (const f4*)(tgt  + (size_t)j0 * D);
        const f4* n1 = (const f4*)(tgt  + (size_t)j1 * D);

        // 24 independent 16B loads, all issued before any use.
        f4 oA[CH], oB[CH], tA[CH], tB[CH], nA[CH], nB[CH];
#pragma unroll
        for (int k = 0; k < CH; ++k)
            oA[k] = __builtin_nontemporal_load(&o0[lane + 64 * k]);
#pragma unroll
        for (int k = 0; k < CH; ++k)
            oB[k] = __builtin_nontemporal_load(&o1[lane + 64 * k]);
#pragma unroll
        for (int k = 0; k < CH; ++k) tA[k] = t0[lane + 64 * k];
#pragma unroll
        for (int k = 0; k < CH; ++k) tB[k] = t1[lane + 64 * k];
#pragma unroll
        for (int k = 0; k < CH; ++k) nA[k] = n0[lane + 64 * k];
#pragma unroll
        for (int k = 0; k < CH; ++k) nB[k] = n1[lane + 64 * k];

        float dtoA = 0.f, dnoA = 0.f, ooA = 0.f, ttA = 0.f, nnA = 0.f;
        float dtoB = 0.f, dnoB = 0.f, ooB = 0.f, ttB = 0.f, nnB = 0.f;
#pragma unroll
        for (int k = 0; k < CH; ++k) {
            dtoA += oA[k].x*tA[k].x + oA[k].y*tA[k].y + oA[k].z*tA[k].z + oA[k].w*tA[k].w;
            dnoA += oA[k].x*nA[k].x + oA[k].y*nA[k].y + oA[k].z*nA[k].z + oA[k].w*nA[k].w;
            ooA  += oA[k].x*oA[k].x + oA[k].y*oA[k].y + oA[k].z*oA[k].z + oA[k].w*oA[k].w;
            ttA  += tA[k].x*tA[k].x + tA[k].y*tA[k].y + tA[k].z*tA[k].z + tA[k].w*tA[k].w;
            nnA  += nA[k].x*nA[k].x + nA[k].y*nA[k].y + nA[k].z*nA[k].z + nA[k].w*nA[k].w;
            dtoB += oB[k].x*tB[k].x + oB[k].y*tB[k].y + oB[k].z*tB[k].z + oB[k].w*tB[k].w;
            dnoB += oB[k].x*nB[k].x + oB[k].y*nB[k].y + oB[k].z*nB[k].z + oB[k].w*nB[k].w;
            ooB  += oB[k].x*oB[k].x + oB[k].y*oB[k].y + oB[k].z*oB[k].z + oB[k].w*oB[k].w;
            ttB  += tB[k].x*tB[k].x + tB[k].y*tB[k].y + tB[k].z*tB[k].z + tB[k].w*tB[k].w;
            nnB  += nB[k].x*nB[k].x + nB[k].y*nB[k].y + nB[k].z*nB[k].z + nB[k].w*nB[k].w;
        }

        dtoA = dpp_wave_sum(dtoA);
        dnoA = dpp_wave_sum(dnoA);
        ooA  = dpp_wave_sum(ooA);
        ttA  = dpp_wave_sum(ttA);
        nnA  = dpp_wave_sum(nnA);
        dtoB = dpp_wave_sum(dtoB);
        dnoB = dpp_wave_sum(dnoB);
        ooB  = dpp_wave_sum(ooB);
        ttB  = dpp_wave_sum(ttB);
        nnB  = dpp_wave_sum(nnB);

        if (lane == 63) {
            float noA   = sqrtf(ooA);
            float h0 = 1.f - dtoA / fmaxf(sqrtf(ttA) * noA, EPS)
                           + dnoA / fmaxf(sqrtf(nnA) * noA, EPS);
            float noB   = sqrtf(ooB);
            float h1 = 1.f - dtoB / fmaxf(sqrtf(ttB) * noB, EPS)
                           + dnoB / fmaxf(sqrtf(nnB) * noB, EPS);
            acc += fmaxf(h0, 0.f) + fmaxf(h1, 0.f);
        }
    }

    // Block-level: lane 63 of each wave holds its partial; one atomic per block.
    __shared__ float red[4];
    if (lane == 63) red[wave] = acc;
    __syncthreads();
    if (threadIdx.x == 0) {
        float s = 0.f;
#pragma unroll
        for (int w = 0; w < 4; ++w) s += red[w];
        atomicAdd(res, s * invB);
    }
}

extern "C" void kernel_launch(void* const* d_in, const int* in_sizes, int n_in,
                              void* d_out, int out_size, void* d_ws, size_t ws_size,
                              hipStream_t stream) {
    const float* outm   = (const float*)d_in[0];
    const float* tgt    = (const float*)d_in[1];
    const int*   negidx = (const int*)d_in[2];
    float* res = (float*)d_out;

    const int B = in_sizes[2];
    const int D = in_sizes[0] / B;

    (void)hipMemsetAsync(res, 0, sizeof(float), stream);

    // 1024 blocks x 256 thr = 4096 waves at 4 waves/EU residency;
    // each wave handles 4 rows as 2 two-row iterations.
    hinge_cos_kernel<<<1024, 256, 0, stream>>>(outm, tgt, negidx, res, B, D,
                                               1.0f / (float)B);
}

// Round 6
// 141.886 us; speedup vs baseline: 1.0979x; 1.0396x over previous
//
#include <hip/hip_runtime.h>
#include <hip/hip_bf16.h>

// Row-wise cosine hinge loss.
//   j = (i + 1 + neg_idx[i]) % B
//   hinge_i = relu(1 - cos(t_i, o_i) + cos(t_j, o_i))
//   out = sum_i hinge_i / B
//
// Wave-per-row with an explicit register double-buffered software pipeline:
// while row i's 12 float4 loads are being consumed (FMA + DPP reduce), row
// i+stride's 12 loads are already in flight in a DISJOINT register buffer.
// This forces ~96 live data VGPRs (compiler cannot recycle them into a
// vmcnt(0) convoy — the R4/R5 failure mode) and keeps per-wave outstanding
// bytes high through the consume phase.

#define EPS 1e-6f

typedef float f4 __attribute__((ext_vector_type(4)));

// VALU-pipe wave reduction via DPP; lane 63 holds the 64-lane sum.
#define DPP_STEP(x, ctrl, rm, bm)                                             \
    x += __int_as_float(__builtin_amdgcn_update_dpp(                          \
        0, __float_as_int(x), (ctrl), (rm), (bm), true))

__device__ __forceinline__ float dpp_wave_sum(float x) {
    DPP_STEP(x, 0x111, 0xf, 0xf);  // row_shr:1
    DPP_STEP(x, 0x112, 0xf, 0xf);  // row_shr:2
    DPP_STEP(x, 0x114, 0xf, 0xe);  // row_shr:4
    DPP_STEP(x, 0x118, 0xf, 0xc);  // row_shr:8
    DPP_STEP(x, 0x142, 0xa, 0xf);  // row_bcast:15
    DPP_STEP(x, 0x143, 0xc, 0xf);  // row_bcast:31
    return x;                      // valid in lane 63
}

struct RowBuf {
    f4 o[4], t[4], n[4];
};

__device__ __forceinline__ void issue_loads(RowBuf& rb,
                                            const float* __restrict__ outm,
                                            const float* __restrict__ tgt,
                                            int i, int j, int lane, int D) {
    const f4* o4 = (const f4*)(outm + (size_t)i * D);
    const f4* t4 = (const f4*)(tgt  + (size_t)i * D);
    const f4* n4 = (const f4*)(tgt  + (size_t)j * D);
#pragma unroll
    for (int k = 0; k < 4; ++k)
        rb.o[k] = __builtin_nontemporal_load(&o4[lane + 64 * k]);  // single-use stream
#pragma unroll
    for (int k = 0; k < 4; ++k) rb.t[k] = t4[lane + 64 * k];
#pragma unroll
    for (int k = 0; k < 4; ++k) rb.n[k] = n4[lane + 64 * k];
}

// Returns this row's hinge value (valid in lane 63; other lanes garbage).
__device__ __forceinline__ float consume(const RowBuf& rb) {
    float dto = 0.f, dno = 0.f, oo = 0.f, tt = 0.f, nn = 0.f;
#pragma unroll
    for (int k = 0; k < 4; ++k) {
        dto += rb.o[k].x*rb.t[k].x + rb.o[k].y*rb.t[k].y + rb.o[k].z*rb.t[k].z + rb.o[k].w*rb.t[k].w;
        dno += rb.o[k].x*rb.n[k].x + rb.o[k].y*rb.n[k].y + rb.o[k].z*rb.n[k].z + rb.o[k].w*rb.n[k].w;
        oo  += rb.o[k].x*rb.o[k].x + rb.o[k].y*rb.o[k].y + rb.o[k].z*rb.o[k].z + rb.o[k].w*rb.o[k].w;
        tt  += rb.t[k].x*rb.t[k].x + rb.t[k].y*rb.t[k].y + rb.t[k].z*rb.t[k].z + rb.t[k].w*rb.t[k].w;
        nn  += rb.n[k].x*rb.n[k].x + rb.n[k].y*rb.n[k].y + rb.n[k].z*rb.n[k].z + rb.n[k].w*rb.n[k].w;
    }
    dto = dpp_wave_sum(dto);
    dno = dpp_wave_sum(dno);
    oo  = dpp_wave_sum(oo);
    tt  = dpp_wave_sum(tt);
    nn  = dpp_wave_sum(nn);
    float no = sqrtf(oo);
    float h  = 1.f - dto / fmaxf(sqrtf(tt) * no, EPS)
                   + dno / fmaxf(sqrtf(nn) * no, EPS);
    return fmaxf(h, 0.f);
}

__global__ __launch_bounds__(256, 4) void hinge_cos_kernel(
    const float* __restrict__ outm,   // [B, D]
    const float* __restrict__ tgt,    // [B, D]
    const int*   __restrict__ negidx, // [B]
    float* __restrict__ res,          // [1] scalar (pre-zeroed)
    int B, int D, float invB) {

    const int lane  = threadIdx.x & 63;
    const int wave  = threadIdx.x >> 6;
    const int wpb   = blockDim.x >> 6;           // 4
    const int gwave = blockIdx.x * wpb + wave;
    const int nwav  = gridDim.x * wpb;           // 4096

    float acc = 0.f;                             // per-wave hinge sum (lane 63)

    RowBuf cur, nxt;
    int i = gwave;
    if (i < B) {
        int j = i + 1 + negidx[i];
        if (j >= B) j -= B;
        issue_loads(cur, outm, tgt, i, j, lane, D);
    }
    while (i < B) {
        const int inext = i + nwav;
        const bool havenext = inext < B;
        if (havenext) {
            // Read the gather index first so the n-load addresses are ready
            // while the o/t loads are being issued.
            int jn = inext + 1 + negidx[inext];
            if (jn >= B) jn -= B;
            issue_loads(nxt, outm, tgt, inext, jn, lane, D);
        }
        float h = consume(cur);                  // overlaps with nxt's loads
        if (lane == 63) acc += h;
        if (havenext) cur = nxt;
        i = inext;
    }

    // Block-level: lane 63 of each wave holds its partial; one atomic per block.
    __shared__ float red[4];
    if (lane == 63) red[wave] = acc;
    __syncthreads();
    if (threadIdx.x == 0) {
        float s = 0.f;
#pragma unroll
        for (int w = 0; w < 4; ++w) s += red[w];
        atomicAdd(res, s * invB);
    }
}

extern "C" void kernel_launch(void* const* d_in, const int* in_sizes, int n_in,
                              void* d_out, int out_size, void* d_ws, size_t ws_size,
                              hipStream_t stream) {
    const float* outm   = (const float*)d_in[0];
    const float* tgt    = (const float*)d_in[1];
    const int*   negidx = (const int*)d_in[2];
    float* res = (float*)d_out;

    const int B = in_sizes[2];
    const int D = in_sizes[0] / B;

    (void)hipMemsetAsync(res, 0, sizeof(float), stream);

    // 1024 blocks x 256 thr = 4096 waves; each wave pipelines 4 rows.
    hinge_cos_kernel<<<1024, 256, 0, stream>>>(outm, tgt, negidx, res, B, D,
                                               1.0f / (float)B);
}